// Round 8
// baseline (631.969 us; speedup 1.0000x reference)
//
#include <hip/hip_runtime.h>
#include <cstdint>

using bf16x8 = __attribute__((ext_vector_type(8))) short;
using f32x4  = __attribute__((ext_vector_type(4))) float;

__device__ __forceinline__ unsigned short f2bf(float f) {
  union { float f; unsigned u; } v; v.f = f;
  unsigned u = v.u;
  u += 0x7fffu + ((u >> 16) & 1u);
  return (unsigned short)(u >> 16);
}
__device__ __forceinline__ float bf2f(unsigned short s) {
  union { unsigned u; float f; } v; v.u = ((unsigned)s) << 16; return v.f;
}

__device__ __forceinline__ void gload_lds16(const unsigned short* g, unsigned short* l) {
  __builtin_amdgcn_global_load_lds(
      (const __attribute__((address_space(1))) unsigned int*)g,
      (__attribute__((address_space(3))) unsigned int*)l, 16, 0, 0);
}

// ---------------- LayerNorm (row of 2048 f32) -> bf16 ----------------
__global__ __launch_bounds__(256) void ln_kernel(
    const float* __restrict__ x, const float* __restrict__ g,
    const float* __restrict__ bb, unsigned short* __restrict__ h)
{
  const int D = 2048;
  const int row = blockIdx.x;
  const float* xr = x + (size_t)row * D;
  const int t = threadIdx.x;
  float4 v0 = ((const float4*)xr)[t];
  float4 v1 = ((const float4*)xr)[t + 256];
  float s  = v0.x+v0.y+v0.z+v0.w + v1.x+v1.y+v1.z+v1.w;
  float ss = v0.x*v0.x+v0.y*v0.y+v0.z*v0.z+v0.w*v0.w
           + v1.x*v1.x+v1.y*v1.y+v1.z*v1.z+v1.w*v1.w;
  #pragma unroll
  for (int off = 1; off < 64; off <<= 1) {
    s  += __shfl_xor(s, off);
    ss += __shfl_xor(ss, off);
  }
  __shared__ float red[8];
  const int wave = t >> 6, lane = t & 63;
  if (lane == 0) { red[wave] = s; red[4+wave] = ss; }
  __syncthreads();
  s  = red[0]+red[1]+red[2]+red[3];
  ss = red[4]+red[5]+red[6]+red[7];
  const float mu   = s * (1.f/2048.f);
  const float var  = ss * (1.f/2048.f) - mu*mu;
  const float rstd = rsqrtf(var + 1e-5f);
  unsigned short* hr = h + (size_t)row * D;
  #pragma unroll
  for (int q = 0; q < 2; ++q) {
    float4 v = q ? v1 : v0;
    int vecidx = t + q*256;
    float4 gg  = ((const float4*)g)[vecidx];
    float4 bv  = ((const float4*)bb)[vecidx];
    ushort4 o;
    o.x = f2bf((v.x-mu)*rstd*gg.x + bv.x);
    o.y = f2bf((v.y-mu)*rstd*gg.y + bv.y);
    o.z = f2bf((v.z-mu)*rstd*gg.z + bv.z);
    o.w = f2bf((v.w-mu)*rstd*gg.w + bv.w);
    *(ushort4*)(hr + vecidx*4) = o;
  }
}

// ---------------- fp32 [K][N] -> bf16 [N][K] transpose+cast ----------------
__global__ __launch_bounds__(256) void transpose_cast(
    const float* __restrict__ W, unsigned short* __restrict__ WT,
    int K, int N)
{
  __shared__ float tile[32][33];
  const int tx = threadIdx.x, ty = threadIdx.y;
  const int n0 = blockIdx.x * 32, k0 = blockIdx.y * 32;
  #pragma unroll
  for (int r = 0; r < 4; ++r)
    tile[ty + r*8][tx] = W[(size_t)(k0 + ty + r*8) * N + n0 + tx];
  __syncthreads();
  #pragma unroll
  for (int r = 0; r < 4; ++r)
    WT[(size_t)(n0 + ty + r*8) * K + k0 + tx] = f2bf(tile[tx][ty + r*8]);
}

// ---------------- split-K reduce: out = bf16(P0)+bf16(P1)+resid(+bias) ----
template<bool BIAS>
__global__ __launch_bounds__(256) void reduce_splitk(
    const unsigned short* __restrict__ P, const float* __restrict__ resid,
    const float* __restrict__ bias, float* __restrict__ out)
{
  const size_t MN8 = (size_t)4096 * 2048 / 8;
  for (size_t i = (size_t)blockIdx.x * 256 + threadIdx.x; i < MN8;
       i += (size_t)gridDim.x * 256) {
    bf16x8 p0 = ((const bf16x8*)P)[i];
    bf16x8 p1 = ((const bf16x8*)P)[i + MN8];
    float4 r0 = ((const float4*)resid)[i*2];
    float4 r1 = ((const float4*)resid)[i*2 + 1];
    float4 b0 = {}, b1 = {};
    if (BIAS) {
      b0 = ((const float4*)bias)[(i & 255) * 2];
      b1 = ((const float4*)bias)[(i & 255) * 2 + 1];
    }
    float4 o0, o1;
    o0.x = bf2f((unsigned short)p0[0]) + bf2f((unsigned short)p1[0]) + r0.x + b0.x;
    o0.y = bf2f((unsigned short)p0[1]) + bf2f((unsigned short)p1[1]) + r0.y + b0.y;
    o0.z = bf2f((unsigned short)p0[2]) + bf2f((unsigned short)p1[2]) + r0.z + b0.z;
    o0.w = bf2f((unsigned short)p0[3]) + bf2f((unsigned short)p1[3]) + r0.w + b0.w;
    o1.x = bf2f((unsigned short)p0[4]) + bf2f((unsigned short)p1[4]) + r1.x + b1.x;
    o1.y = bf2f((unsigned short)p0[5]) + bf2f((unsigned short)p1[5]) + r1.y + b1.y;
    o1.z = bf2f((unsigned short)p0[6]) + bf2f((unsigned short)p1[6]) + r1.z + b1.z;
    o1.w = bf2f((unsigned short)p0[7]) + bf2f((unsigned short)p1[7]) + r1.w + b1.w;
    ((float4*)out)[i*2]     = o0;
    ((float4*)out)[i*2 + 1] = o1;
  }
}

// ---------------- m201-style 8-phase bf16 GEMM ----------------
// C[M][N] = A[M][K] @ BT[N][K]^T. BM=BN=256, BK=64, 8 waves (2Mx4N), 512 thr.
// Per phase p (4 phases/K-tile): {ds-reads for THIS phase's MFMA (A mi-pair p:
// 4 reads; +8 B reads at p0); 2 staged gloads; counted vmcnt at p1/p3;
// s_barrier; lgkmcnt(0); sched_barrier(0); setprio(1); 16 MFMA; setprio(0);
// s_barrier}. Overlap via per-wave staggered lgkm completion after the mid
// barrier (DS queue drains under early waves' MFMA).
// Stage schedule for tile T (quarters into buf(T&1)); death/landing verified:
//   T-2.p1: B0,B1   T-2.p2: B2,B3   T-2.p3: A0,A2   T-1.p0: A1,A3
// vmcnt(8) at p3 covers next tile's B+A0+A2; vmcnt(10) at p1 covers A1,A3.
template<bool BIAS, bool RELU, bool RESID, bool OUTBF16>
__global__ __launch_bounds__(512, 2) void gemm10(
    const unsigned short* __restrict__ A, const unsigned short* __restrict__ BT,
    const float* __restrict__ bias, const float* __restrict__ resid,
    void* __restrict__ Cp, int M, int N, int K, int kdepth, int nbx, int ntiles)
{
  constexpr int BM = 256, BN = 256, BK = 64;
  __shared__ __align__(16) unsigned short lds[2][(BM + BN) * BK];  // 128 KB

  const int tid  = threadIdx.x;
  const int lane = tid & 63, wave = tid >> 6;
  const int l15 = lane & 15, lh = lane >> 4;
  const int wr = wave >> 2, wc = wave & 3;

  const int nwg = gridDim.x, q8 = nwg >> 3, wg = blockIdx.x;
  const int swz = (wg & 7) * q8 + (wg >> 3);
  const int split = swz / ntiles;
  const int tile  = swz % ntiles;
  const size_t bm = (size_t)(tile / nbx) * BM;
  const size_t bn = (size_t)(tile % nbx) * BN;
  A  += (size_t)split * kdepth;
  BT += (size_t)split * kdepth;
  const int nk = kdepth >> 6;

  // staging: thread -> (row = qq*64 + tid>>3, chunk sc inverse-swizzled)
  const int srow = tid >> 3;
  const int sc   = (tid & 7) ^ (srow & 7);
  const unsigned short* aSrc = A  + (bm + srow) * (size_t)K + sc * 8;
  const unsigned short* bSrc = BT + (bn + srow) * (size_t)K + sc * 8;
  const size_t qStride = (size_t)64 * K;

  // fragment-read swizzled chunk offsets (bytes)
  const int aswz = (l15 & 7) << 4;
  const int rx0 = (lh * 16) ^ aswz;          // kk=0
  const int rx1 = (64 + lh * 16) ^ aswz;     // kk=1
  char* const lbase = (char*)&lds[0][0];

  bf16x8 af[2][2];        // A-frags for current phase (mi x kk)
  bf16x8 bfr[2][4];       // B-frags, resident per K-tile
  f32x4  acc[8][4] = {};

  auto stA = [&](int buf, int kt2, int qq) {
    gload_lds16(aSrc + (size_t)kt2 * BK + qq * qStride,
                &lds[buf][qq * 4096 + tid * 8]);
  };
  auto stB = [&](int buf, int kt2, int qq) {
    gload_lds16(bSrc + (size_t)kt2 * BK + qq * qStride,
                &lds[buf][BM * BK + qq * 4096 + tid * 8]);
  };
  // A-frags for phase p: rows wr*128 + p*32 + mi*16 + l15
  //   quarter q = wr*2 + p/2; within-quarter row = (p&1)*32 + mi*16 + l15
  auto rdA = [&](int buf, int p) {
    const char* pa = lbase + buf * 65536 + (wr*2 + (p >> 1)) * 8192
                   + ((p & 1) * 32 + l15) * 128;
    af[0][0] = *(const bf16x8*)(pa + rx0);
    af[0][1] = *(const bf16x8*)(pa + rx1);
    af[1][0] = *(const bf16x8*)(pa + 2048 + rx0);
    af[1][1] = *(const bf16x8*)(pa + 2048 + rx1);
  };
  auto rdB8 = [&](int buf) {
    const char* p = lbase + buf * 65536 + 32768 + (wc*64 + l15) * 128;
    #pragma unroll
    for (int n = 0; n < 4; ++n) {
      bfr[0][n] = *(const bf16x8*)(p + n*2048 + rx0);
      bfr[1][n] = *(const bf16x8*)(p + n*2048 + rx1);
    }
  };

#define CLUSTER(P)                                                         \
  __builtin_amdgcn_s_setprio(1);                                           \
  { _Pragma("unroll")                                                      \
    for (int mi = 0; mi < 2; ++mi)                                         \
      { _Pragma("unroll")                                                  \
        for (int n = 0; n < 4; ++n)                                        \
          { _Pragma("unroll")                                              \
            for (int kk = 0; kk < 2; ++kk)                                 \
              acc[(P)*2+mi][n] = __builtin_amdgcn_mfma_f32_16x16x32_bf16(  \
                  af[mi][kk], bfr[kk][n], acc[(P)*2+mi][n], 0, 0, 0);      \
          } } }                                                            \
  __builtin_amdgcn_s_setprio(0);
#define BAR() asm volatile("" ::: "memory"); __builtin_amdgcn_s_barrier(); \
              asm volatile("" ::: "memory")
#define WAITL0() asm volatile("s_waitcnt lgkmcnt(0)" ::: "memory");        \
                 __builtin_amdgcn_sched_barrier(0)

  // ---- prologue: tile0 fully (8), tile1 partial (6); A1,A3(1) at T0.p0 ----
  stB(0,0,0); stB(0,0,1); stB(0,0,2); stB(0,0,3);
  stA(0,0,0); stA(0,0,2); stA(0,0,1); stA(0,0,3);
  if (nk > 1) {
    stB(1,1,0); stB(1,1,1); stB(1,1,2); stB(1,1,3);
    stA(1,1,0); stA(1,1,2);
    asm volatile("s_waitcnt vmcnt(6)" ::: "memory");
  } else {
    asm volatile("s_waitcnt vmcnt(0)" ::: "memory");
  }
  BAR();

  for (int kt = 0; kt < nk; ++kt) {
    const int buf = kt & 1, nb = buf ^ 1;
    const bool pf = (kt + 2 < nk);
    // ---------- phase 0 ----------
    rdA(buf, 0); rdB8(buf);
    if (kt + 1 < nk) { stA(nb, kt+1, 1); stA(nb, kt+1, 3); }
    asm volatile("s_waitcnt lgkmcnt(8)" ::: "memory");
    BAR();
    WAITL0();
    CLUSTER(0);
    BAR();
    // ---------- phase 1 ----------
    rdA(buf, 1);
    if (pf) { stB(buf, kt+2, 0); stB(buf, kt+2, 1); }
    asm volatile("s_waitcnt vmcnt(10)" ::: "memory");
    BAR();
    WAITL0();
    CLUSTER(1);
    BAR();
    // ---------- phase 2 ----------
    rdA(buf, 2);
    if (pf) { stB(buf, kt+2, 2); stB(buf, kt+2, 3); }
    BAR();
    WAITL0();
    CLUSTER(2);
    BAR();
    // ---------- phase 3 ----------
    rdA(buf, 3);
    if (pf) { stA(buf, kt+2, 0); stA(buf, kt+2, 2); }
    asm volatile("s_waitcnt vmcnt(8)" ::: "memory");
    BAR();
    WAITL0();
    CLUSTER(3);
    BAR();
  }
#undef CLUSTER
#undef BAR
#undef WAITL0

  // ---- epilogue: rows bm + wr*128 + p*32 + mi*16 + lh*4 + r ----
  float bv[4];
  if (BIAS) {
    #pragma unroll
    for (int n = 0; n < 4; ++n) bv[n] = bias[bn + wc*64 + n*16 + l15];
  }
  unsigned short* Cb = (unsigned short*)Cp + (size_t)split * M * N;
  float*          Cf = (float*)Cp + (size_t)split * M * N;
  #pragma unroll
  for (int p = 0; p < 4; ++p) {
    #pragma unroll
    for (int mi = 0; mi < 2; ++mi) {
      #pragma unroll
      for (int r = 0; r < 4; ++r) {
        size_t rrow = bm + (size_t)wr*128 + p*32 + mi*16 + lh*4 + r;
        #pragma unroll
        for (int n = 0; n < 4; ++n) {
          size_t ccol = bn + wc*64 + n*16 + l15;
          float v = acc[p*2+mi][n][r];
          if (BIAS)  v += bv[n];
          if (RELU)  v = fmaxf(v, 0.f);
          if (RESID) v += resid[rrow*(size_t)N + ccol];
          if (OUTBF16) Cb[rrow*(size_t)N + ccol] = f2bf(v);
          else         Cf[rrow*(size_t)N + ccol] = v;
        }
      }
    }
  }
}

// ---------------- fused causal attention (unchanged) ----------------
__global__ __launch_bounds__(256) void attn_kernel(
    const unsigned short* __restrict__ QKV, unsigned short* __restrict__ O)
{
  constexpr float SCALE = 0.08838834764831845f;  // 1/sqrt(128)
  __shared__ __align__(16) unsigned short Kl[64*128];
  __shared__ __align__(16) unsigned short Vf[64*128];
  __shared__ __align__(16) unsigned short Pl[4*1024];
  const int bid = blockIdx.x;
  const int qt = 31 - (bid >> 5);
  const int nh = bid & 15;
  const int b  = (bid >> 4) & 1;
  const int t = threadIdx.x;
  const int lane = t & 63, wave = t >> 6;
  const int l15 = lane & 15, lh = lane >> 4;
  const int i0 = qt*64 + wave*16;
  const size_t RS = 6144;
  const size_t base = (size_t)b * 2048 * RS;

  const unsigned short* qrow = QKV + base + (size_t)(nh*128 + (i0 >> 4)) * RS;
  bf16x8 qf[4];
  #pragma unroll
  for (int c = 0; c < 4; ++c)
    qf[c] = *(const bf16x8*)(qrow + l15*128 + c*32 + lh*8);

  f32x4 of[8] = {};
  float mrun[4], lrun[4];
  #pragma unroll
  for (int r = 0; r < 4; ++r) { mrun[r] = -INFINITY; lrun[r] = 0.f; }

  const int nkt = qt + 1;
  bf16x8 kr[4], vr[4];
  auto loadKV = [&](int kt) {
    #pragma unroll
    for (int q = 0; q < 4; ++q) {
      int c = t + q*256;
      int j = c >> 4, dd0 = (c & 15) * 8;
      const size_t grow = base + (size_t)(nh*128 + kt*4 + (j >> 4)) * RS + (j & 15)*128 + dd0;
      kr[q] = *(const bf16x8*)(QKV + grow + 2048);
      vr[q] = *(const bf16x8*)(QKV + grow + 4096);
    }
  };
  loadKV(0);

  for (int kt = 0; kt < nkt; ++kt) {
    __syncthreads();
    #pragma unroll
    for (int q = 0; q < 4; ++q) {
      int c = t + q*256;
      int j = c >> 4, dd0 = (c & 15) * 8;
      *(bf16x8*)((char*)Kl + ((j*256 + dd0*2) ^ ((j & 7) << 4))) = kr[q];
      int ks = j >> 5, jq = j & 31;
      int cc = dd0 >> 4;
      int wb = ks*8192 + cc*1024 + (((dd0 & 15) + 16*((jq >> 3) & 3)) & ~7)*16 + (jq & 7)*2;
      #pragma unroll
      for (int e = 0; e < 8; ++e)
        *(unsigned short*)((char*)Vf + wb + ((e ^ cc) * 16)) = (unsigned short)vr[q][e];
    }
    __syncthreads();
    if (kt + 1 < nkt) loadKV(kt + 1);

    f32x4 sc[4] = {};
    #pragma unroll
    for (int jt = 0; jt < 4; ++jt) {
      int row = jt*16 + l15;
      const char* kb = (const char*)Kl + row*256;
      const int sw = (row & 7) << 4;
      #pragma unroll
      for (int c = 0; c < 4; ++c) {
        bf16x8 kf = *(const bf16x8*)(kb + ((c*64 + lh*16) ^ sw));
        sc[jt] = __builtin_amdgcn_mfma_f32_16x16x32_bf16(qf[c], kf, sc[jt], 0, 0, 0);
      }
    }

    float fac[4];
    char* pw = (char*)Pl + wave*2048;
    #pragma unroll
    for (int r = 0; r < 4; ++r) {
      float s0 = sc[0][r]*SCALE, s1 = sc[1][r]*SCALE, s2 = sc[2][r]*SCALE, s3 = sc[3][r]*SCALE;
      if (kt == qt) {
        const int i = i0 + lh*4 + r;
        const int j = kt*64 + l15;
        s0 = (j      > i) ? -INFINITY : s0;
        s1 = (j + 16 > i) ? -INFINITY : s1;
        s2 = (j + 32 > i) ? -INFINITY : s2;
        s3 = (j + 48 > i) ? -INFINITY : s3;
      }
      float mx = fmaxf(fmaxf(s0, s1), fmaxf(s2, s3));
      #pragma unroll
      for (int mk = 1; mk < 16; mk <<= 1) mx = fmaxf(mx, __shfl_xor(mx, mk));
      const float mnew = fmaxf(mrun[r], mx);
      float p0 = __expf(s0 - mnew), p1 = __expf(s1 - mnew);
      float p2 = __expf(s2 - mnew), p3 = __expf(s3 - mnew);
      float psum = (p0 + p1) + (p2 + p3);
      #pragma unroll
      for (int mk = 1; mk < 16; mk <<= 1) psum += __shfl_xor(psum, mk);
      fac[r]  = __expf(mrun[r] - mnew);
      lrun[r] = lrun[r]*fac[r] + psum;
      mrun[r] = mnew;
      const int io = lh*4 + r;
      const int swp = (io & 7) << 4;
      char* pr = pw + io*128;
      *(unsigned short*)(pr + ((     l15*2) ^ swp)) = f2bf(p0);
      *(unsigned short*)(pr + ((32 + l15*2) ^ swp)) = f2bf(p1);
      *(unsigned short*)(pr + ((64 + l15*2) ^ swp)) = f2bf(p2);
      *(unsigned short*)(pr + ((96 + l15*2) ^ swp)) = f2bf(p3);
    }
    #pragma unroll
    for (int c = 0; c < 8; ++c)
      #pragma unroll
      for (int r = 0; r < 4; ++r)
        of[c][r] *= fac[r];

    const char* prd = pw + l15*128;
    const int psw = (l15 & 7) << 4;
    bf16x8 pa0 = *(const bf16x8*)(prd + ((     lh*16) ^ psw));
    bf16x8 pa1 = *(const bf16x8*)(prd + ((64 + lh*16) ^ psw));

    #pragma unroll
    for (int c = 0; c < 8; ++c) {
      const char* vb = (const char*)Vf + c*1024 + ((lane ^ c) * 16);
      bf16x8 v0 = *(const bf16x8*)(vb);
      bf16x8 v1 = *(const bf16x8*)(vb + 8192);
      of[c] = __builtin_amdgcn_mfma_f32_16x16x32_bf16(pa0, v0, of[c], 0, 0, 0);
      of[c] = __builtin_amdgcn_mfma_f32_16x16x32_bf16(pa1, v1, of[c], 0, 0, 0);
    }
  }

  unsigned short* orow = O + ((size_t)(b*2048 + i0))*2048 + nh*128;
  #pragma unroll
  for (int r = 0; r < 4; ++r) {
    const float inv = 1.f / lrun[r];
    #pragma unroll
    for (int c = 0; c < 8; ++c)
      orow[(size_t)(lh*4 + r)*2048 + c*16 + l15] = f2bf(of[c][r]*inv);
  }
}

// ---------------- launcher ----------------
extern "C" void kernel_launch(void* const* d_in, const int* in_sizes, int n_in,
                              void* d_out, int out_size, void* d_ws, size_t ws_size,
                              hipStream_t stream)
{
  const float* x    = (const float*)d_in[0];
  const float* Wq   = (const float*)d_in[2];
  const float* Wk   = (const float*)d_in[3];
  const float* Wv   = (const float*)d_in[4];
  const float* Wo   = (const float*)d_in[5];
  const float* ln1g = (const float*)d_in[6];
  const float* ln1b = (const float*)d_in[7];
  const float* W1   = (const float*)d_in[8];
  const float* b1   = (const float*)d_in[9];
  const float* W2   = (const float*)d_in[10];
  const float* b2   = (const float*)d_in[11];
  const float* ln2g = (const float*)d_in[12];
  const float* ln2b = (const float*)d_in[13];
  float* out = (float*)d_out;

  char* ws = (char*)d_ws;
  unsigned short* WqkvT  = (unsigned short*)(ws);                  // [6144][2048] bf16
  unsigned short* WoT    = (unsigned short*)(ws + 25165824);       // [2048][2048]
  unsigned short* W1T    = (unsigned short*)(ws + 33554432);       // [8192][2048]
  unsigned short* W2T    = (unsigned short*)(ws + 67108864);       // [2048][8192]
  unsigned short* h      = (unsigned short*)(ws + 100663296);      // [4096][2048]
  float*          x2     = (float*)(ws + 117440512);               // [4096][2048] f32
  unsigned short* QKV    = (unsigned short*)(ws + 150994944);      // [4096][6144]
  unsigned short* attn_o = (unsigned short*)(ws + 201326592);      // [4096][2048]
  unsigned short* ff1    = (unsigned short*)(ws + 150994944);      // [4096][8192]
  unsigned short* Pwo    = (unsigned short*)(ws + 150994944);      // [2][4096][2048] bf16 (QKV region, dead post-attn)
  unsigned short* Pw2    = (unsigned short*)(ws);                  // [2][4096][2048] bf16 (WqkvT+WoT region, dead at W2)

  dim3 tb(32, 8);
  transpose_cast<<<dim3(64, 64),  tb, 0, stream>>>(Wq, WqkvT,                2048, 2048);
  transpose_cast<<<dim3(64, 64),  tb, 0, stream>>>(Wk, WqkvT + 2048*2048,    2048, 2048);
  transpose_cast<<<dim3(64, 64),  tb, 0, stream>>>(Wv, WqkvT + 2*2048*2048,  2048, 2048);
  transpose_cast<<<dim3(64, 64),  tb, 0, stream>>>(Wo, WoT,                  2048, 2048);
  transpose_cast<<<dim3(256, 64), tb, 0, stream>>>(W1, W1T,                  2048, 8192);
  transpose_cast<<<dim3(64, 256), tb, 0, stream>>>(W2, W2T,                  8192, 2048);

  ln_kernel<<<4096, 256, 0, stream>>>(x, ln1g, ln1b, h);
  // QKV = h @ [Wq|Wk|Wv]  (M=4096, N=6144, K=2048): 16x24 = 384 blocks
  gemm10<false,false,false,true><<<384, 512, 0, stream>>>(
      h, WqkvT, nullptr, nullptr, QKV, 4096, 6144, 2048, 2048, 24, 384);
  attn_kernel<<<1024, 256, 0, stream>>>(QKV, attn_o);
  // Wo split-K=2: Pwo[s] = attn_o[:, s*1024:] @ WoT-half  (bf16 partials)
  gemm10<false,false,false,true><<<256, 512, 0, stream>>>(
      attn_o, WoT, nullptr, nullptr, Pwo, 4096, 2048, 2048, 1024, 8, 128);
  // x2 = P0 + P1 + x
  reduce_splitk<false><<<2048, 256, 0, stream>>>(Pwo, x, nullptr, x2);
  ln_kernel<<<4096, 256, 0, stream>>>(x2, ln2g, ln2b, h);
  // ff1 = relu(h2 @ W1 + b1)  (N=8192): 16x32 = 512 blocks
  gemm10<true,true,false,true><<<512, 512, 0, stream>>>(
      h, W1T, b1, nullptr, ff1, 4096, 8192, 2048, 2048, 32, 512);
  // W2 split-K=2: Pw2[s] = ff1[:, s*4096:] @ W2T-half  (bf16 partials)
  gemm10<false,false,false,true><<<256, 512, 0, stream>>>(
      ff1, W2T, nullptr, nullptr, Pw2, 4096, 2048, 8192, 4096, 8, 128);
  // out = P0 + P1 + x2 + b2
  reduce_splitk<true><<<2048, 256, 0, stream>>>(Pw2, x2, b2, out);
}

// Round 9
// 597.673 us; speedup vs baseline: 1.0574x; 1.0574x over previous
//
#include <hip/hip_runtime.h>
#include <cstdint>

using bf16x8 = __attribute__((ext_vector_type(8))) short;
using f32x4  = __attribute__((ext_vector_type(4))) float;

__device__ __forceinline__ unsigned short f2bf(float f) {
  union { float f; unsigned u; } v; v.f = f;
  unsigned u = v.u;
  u += 0x7fffu + ((u >> 16) & 1u);
  return (unsigned short)(u >> 16);
}

__device__ __forceinline__ void gload_lds16(const unsigned short* g, unsigned short* l) {
  __builtin_amdgcn_global_load_lds(
      (const __attribute__((address_space(1))) unsigned int*)g,
      (__attribute__((address_space(3))) unsigned int*)l, 16, 0, 0);
}

// ---------------- LayerNorm (row of 2048 f32) -> bf16 ----------------
__global__ __launch_bounds__(256) void ln_kernel(
    const float* __restrict__ x, const float* __restrict__ g,
    const float* __restrict__ bb, unsigned short* __restrict__ h)
{
  const int D = 2048;
  const int row = blockIdx.x;
  const float* xr = x + (size_t)row * D;
  const int t = threadIdx.x;
  float4 v0 = ((const float4*)xr)[t];
  float4 v1 = ((const float4*)xr)[t + 256];
  float s  = v0.x+v0.y+v0.z+v0.w + v1.x+v1.y+v1.z+v1.w;
  float ss = v0.x*v0.x+v0.y*v0.y+v0.z*v0.z+v0.w*v0.w
           + v1.x*v1.x+v1.y*v1.y+v1.z*v1.z+v1.w*v1.w;
  #pragma unroll
  for (int off = 1; off < 64; off <<= 1) {
    s  += __shfl_xor(s, off);
    ss += __shfl_xor(ss, off);
  }
  __shared__ float red[8];
  const int wave = t >> 6, lane = t & 63;
  if (lane == 0) { red[wave] = s; red[4+wave] = ss; }
  __syncthreads();
  s  = red[0]+red[1]+red[2]+red[3];
  ss = red[4]+red[5]+red[6]+red[7];
  const float mu   = s * (1.f/2048.f);
  const float var  = ss * (1.f/2048.f) - mu*mu;
  const float rstd = rsqrtf(var + 1e-5f);
  unsigned short* hr = h + (size_t)row * D;
  #pragma unroll
  for (int q = 0; q < 2; ++q) {
    float4 v = q ? v1 : v0;
    int vecidx = t + q*256;
    float4 gg  = ((const float4*)g)[vecidx];
    float4 bv  = ((const float4*)bb)[vecidx];
    ushort4 o;
    o.x = f2bf((v.x-mu)*rstd*gg.x + bv.x);
    o.y = f2bf((v.y-mu)*rstd*gg.y + bv.y);
    o.z = f2bf((v.z-mu)*rstd*gg.z + bv.z);
    o.w = f2bf((v.w-mu)*rstd*gg.w + bv.w);
    *(ushort4*)(hr + vecidx*4) = o;
  }
}

// ------- batched fp32 [2048][2048] -> bf16 [2048][2048]^T transpose+cast ----
struct TPArgs { const float* src[4]; unsigned short* dst[4]; };
__global__ __launch_bounds__(256) void transpose_cast4(TPArgs args)
{
  const float* W = args.src[blockIdx.z];
  unsigned short* WT = args.dst[blockIdx.z];
  const int K = 2048, N = 2048;
  __shared__ float tile[32][33];
  const int tx = threadIdx.x, ty = threadIdx.y;
  const int n0 = blockIdx.x * 32, k0 = blockIdx.y * 32;
  #pragma unroll
  for (int r = 0; r < 4; ++r)
    tile[ty + r*8][tx] = W[(size_t)(k0 + ty + r*8) * N + n0 + tx];
  __syncthreads();
  #pragma unroll
  for (int r = 0; r < 4; ++r)
    WT[(size_t)(n0 + ty + r*8) * K + k0 + tx] = f2bf(tile[tx][ty + r*8]);
}

__global__ __launch_bounds__(256) void transpose_cast(
    const float* __restrict__ W, unsigned short* __restrict__ WT,
    int K, int N)
{
  __shared__ float tile[32][33];
  const int tx = threadIdx.x, ty = threadIdx.y;
  const int n0 = blockIdx.x * 32, k0 = blockIdx.y * 32;
  #pragma unroll
  for (int r = 0; r < 4; ++r)
    tile[ty + r*8][tx] = W[(size_t)(k0 + ty + r*8) * N + n0 + tx];
  __syncthreads();
  #pragma unroll
  for (int r = 0; r < 4; ++r)
    WT[(size_t)(n0 + ty + r*8) * K + k0 + tx] = f2bf(tile[tx][ty + r*8]);
}

// ---------------- split-K reduce: out = x2 + P0 + P1 + b2 (f32) ----------------
__global__ __launch_bounds__(256) void reduce_splitk(
    const float* __restrict__ P, const float* __restrict__ x2,
    const float* __restrict__ b2, float* __restrict__ out)
{
  const size_t MN4 = (size_t)4096 * 2048 / 4;
  const float4* P0 = (const float4*)P;
  const float4* P1 = P0 + MN4;
  const float4* X  = (const float4*)x2;
  const float4* B  = (const float4*)b2;
  for (size_t i = (size_t)blockIdx.x * 256 + threadIdx.x; i < MN4;
       i += (size_t)gridDim.x * 256) {
    float4 a = P0[i], b = P1[i], c = X[i], bb = B[i & 511];
    float4 o;
    o.x = a.x + b.x + c.x + bb.x;
    o.y = a.y + b.y + c.y + bb.y;
    o.z = a.z + b.z + c.z + bb.z;
    o.w = a.w + b.w + c.w + bb.w;
    ((float4*)out)[i] = o;
  }
}

// ---------------- phased bf16 GEMM, reg-prefetch pipeline (R6-benched) ----
template<int BM, bool BIAS, bool RELU, bool RESID, bool OUTBF16>
__global__ __launch_bounds__(512, 2) void gemm8(
    const unsigned short* __restrict__ A, const unsigned short* __restrict__ BT,
    const float* __restrict__ bias, const float* __restrict__ resid,
    void* __restrict__ Cp, int M, int N, int K, int kdepth, int nbx, int ntiles)
{
  constexpr int BN = 256, BK = 64;
  constexpr int MPH = BM / 64;           // phases per K-tile (4 or 2)
  constexpr int AQ  = BM / 64;           // A stage-quarters (64 rows each)
  constexpr int LPK = AQ + 4;            // loads per K-tile per thread
  __shared__ __align__(16) unsigned short lds[2][(BM + BN) * BK];

  const int tid  = threadIdx.x;
  const int lane = tid & 63, wave = tid >> 6;
  const int l15 = lane & 15, lh = lane >> 4;
  const int wr = wave >> 2, wc = wave & 3;

  const int nwg = gridDim.x, q8 = nwg >> 3, wg = blockIdx.x;
  const int swz = (wg & 7) * q8 + (wg >> 3);
  const int split = swz / ntiles;
  const int tile  = swz % ntiles;
  const size_t bm = (size_t)(tile / nbx) * BM;
  const size_t bn = (size_t)(tile % nbx) * BN;
  A  += (size_t)split * kdepth;
  BT += (size_t)split * kdepth;
  const int nk = kdepth >> 6;

  auto stageA = [&](int buf, int kt, int qq) {
    int idx = qq * 512 + tid;
    int row = idx >> 3, c = idx & 7, gc = c ^ (row & 7);
    gload_lds16(A + (bm + row) * (size_t)K + (size_t)kt * BK + gc * 8,
                &lds[buf][0] + idx * 8);
  };
  auto stageB = [&](int buf, int kt, int qq) {
    int idx = qq * 512 + tid;
    int row = idx >> 3, c = idx & 7, gc = c ^ (row & 7);
    gload_lds16(BT + (bn + row) * (size_t)K + (size_t)kt * BK + gc * 8,
                &lds[buf][BM * BK] + idx * 8);
  };

  f32x4 acc[MPH * 2][4] = {};

  #pragma unroll
  for (int qq = 0; qq < AQ; ++qq) stageA(0, 0, qq);
  #pragma unroll
  for (int qq = 0; qq < 4; ++qq)  stageB(0, 0, qq);
  #pragma unroll
  for (int qq = 0; qq < AQ; ++qq) stageA(1, 1, qq);
  #pragma unroll
  for (int qq = 0; qq < 4; ++qq)  stageB(1, 1, qq);

  for (int kt = 0; kt < nk; ++kt) {
    const int buf = kt & 1;
    if (kt < nk - 1) asm volatile("s_waitcnt vmcnt(%0)" :: "i"(LPK) : "memory");
    else             asm volatile("s_waitcnt vmcnt(0)" ::: "memory");
    __builtin_amdgcn_s_barrier();
    asm volatile("" ::: "memory");

    const unsigned short* La = &lds[buf][0];
    const unsigned short* Lb = &lds[buf][BM * BK];
    const bool pf = (kt + 2 < nk);

    bf16x8 af[MPH][2][2];
    #pragma unroll
    for (int mi = 0; mi < 2; ++mi) {
      int arow = (wr * 2 + mi) * 16 + l15;
      #pragma unroll
      for (int kk = 0; kk < 2; ++kk)
        af[0][mi][kk] = *(const bf16x8*)(La + arow * 64 +
                          ((kk * 32 + lh * 8) ^ ((arow & 7) << 3)));
    }
    bf16x8 bfr[2][4];
    #pragma unroll
    for (int kk = 0; kk < 2; ++kk)
      #pragma unroll
      for (int n = 0; n < 4; ++n) {
        int brow = wc * 64 + n * 16 + l15;
        bfr[kk][n] = *(const bf16x8*)(Lb + brow * 64 +
                       ((kk * 32 + lh * 8) ^ ((brow & 7) << 3)));
      }

    #pragma unroll
    for (int p = 0; p < MPH; ++p) {
      if (p + 1 < MPH) {
        #pragma unroll
        for (int mi = 0; mi < 2; ++mi) {
          int arow = ((p + 1) * 4 + wr * 2 + mi) * 16 + l15;
          #pragma unroll
          for (int kk = 0; kk < 2; ++kk)
            af[p + 1][mi][kk] = *(const bf16x8*)(La + arow * 64 +
                                  ((kk * 32 + lh * 8) ^ ((arow & 7) << 3)));
        }
      }
      if (p > 0 && pf) {
        if (MPH == 4) { stageA(buf, kt + 2, p - 1); stageB(buf, kt + 2, p - 1); }
        else          { stageA(buf, kt + 2, 0);
                        stageB(buf, kt + 2, 0); stageB(buf, kt + 2, 1); }
      }
      __builtin_amdgcn_sched_barrier(0);
      __builtin_amdgcn_s_setprio(1);
      #pragma unroll
      for (int mi = 0; mi < 2; ++mi)
        #pragma unroll
        for (int n = 0; n < 4; ++n)
          #pragma unroll
          for (int kk = 0; kk < 2; ++kk)
            acc[p*2+mi][n] = __builtin_amdgcn_mfma_f32_16x16x32_bf16(
                af[p][mi][kk], bfr[kk][n], acc[p*2+mi][n], 0, 0, 0);
      __builtin_amdgcn_s_setprio(0);
      asm volatile("" ::: "memory");
      __builtin_amdgcn_s_barrier();
    }
    if (pf) {
      if (MPH == 4) { stageA(buf, kt + 2, 3); stageB(buf, kt + 2, 3); }
      else          { stageA(buf, kt + 2, 1);
                      stageB(buf, kt + 2, 2); stageB(buf, kt + 2, 3); }
    }
  }

  float bv[4];
  if (BIAS) {
    #pragma unroll
    for (int n = 0; n < 4; ++n) bv[n] = bias[bn + wc*64 + n*16 + l15];
  }
  unsigned short* Cb = (unsigned short*)Cp + (size_t)split * M * N;
  float*          Cf = (float*)Cp + (size_t)split * M * N;
  #pragma unroll
  for (int p = 0; p < MPH; ++p) {
    #pragma unroll
    for (int mi = 0; mi < 2; ++mi) {
      #pragma unroll
      for (int r = 0; r < 4; ++r) {
        size_t rrow = bm + (size_t)(p*4 + wr*2 + mi)*16 + lh*4 + r;
        #pragma unroll
        for (int n = 0; n < 4; ++n) {
          size_t ccol = bn + wc*64 + n*16 + l15;
          float v = acc[p*2+mi][n][r];
          if (BIAS)  v += bv[n];
          if (RELU)  v = fmaxf(v, 0.f);
          if (RESID) v += resid[rrow*(size_t)N + ccol];
          if (OUTBF16) Cb[rrow*(size_t)N + ccol] = f2bf(v);
          else         Cf[rrow*(size_t)N + ccol] = v;
        }
      }
    }
  }
}

// ---------------- fused causal attention v3: QBLK=128, 8 waves ----------------
// QKV: [4096][6144] bf16 (Q cols 0..2047, K 2048..4095, V 4096..6143)
// head nh, token p -> QKV row b*2048 + nh*128 + (p>>4), col chunk (p&15)*128
// 512 threads = 8 waves x 16 q-rows; KVBLK=64 staged once per 128 q-rows.
__global__ __launch_bounds__(512) void attn_kernel(
    const unsigned short* __restrict__ QKV, unsigned short* __restrict__ O)
{
  constexpr float SCALE = 0.08838834764831845f;  // 1/sqrt(128)
  __shared__ __align__(16) unsigned short Kl[64*128];   // 16 KB row-XOR
  __shared__ __align__(16) unsigned short Vf[64*128];   // 16 KB frag-order
  __shared__ __align__(16) unsigned short Pl[8*1024];   // 16 KB per-wave P
  const int bid = blockIdx.x;
  const int qtb = 15 - (bid >> 5);       // heavy q-tiles first
  const int nh = bid & 15;
  const int b  = (bid >> 4) & 1;
  const int t = threadIdx.x;
  const int lane = t & 63, wave = t >> 6;
  const int l15 = lane & 15, lh = lane >> 4;
  const int i0 = qtb*128 + wave*16;      // this wave's 16 q-rows
  const int dt = i0 >> 6;                // wave's diagonal 64-tile
  const size_t RS = 6144;
  const size_t base = (size_t)b * 2048 * RS;

  const unsigned short* qrow = QKV + base + (size_t)(nh*128 + (i0 >> 4)) * RS;
  bf16x8 qf[4];
  #pragma unroll
  for (int c = 0; c < 4; ++c)
    qf[c] = *(const bf16x8*)(qrow + l15*128 + c*32 + lh*8);

  f32x4 of[8] = {};
  float mrun[4], lrun[4];
  #pragma unroll
  for (int r = 0; r < 4; ++r) { mrun[r] = -INFINITY; lrun[r] = 0.f; }

  const int nkt = 2*qtb + 2;             // 64-tiles covering rows <= qtb*128+127
  bf16x8 kr[2], vr[2];
  auto loadKV = [&](int kt) {
    #pragma unroll
    for (int q = 0; q < 2; ++q) {
      int c = t + q*512;                 // 0..1023
      int j = c >> 4, dd0 = (c & 15) * 8;
      const size_t grow = base + (size_t)(nh*128 + kt*4 + (j >> 4)) * RS + (j & 15)*128 + dd0;
      kr[q] = *(const bf16x8*)(QKV + grow + 2048);
      vr[q] = *(const bf16x8*)(QKV + grow + 4096);
    }
  };
  loadKV(0);

  for (int kt = 0; kt < nkt; ++kt) {
    __syncthreads();   // previous tile's LDS reads done
    // ---- store K (vector, row-XOR) + V (frag-order scatter) ----
    #pragma unroll
    for (int q = 0; q < 2; ++q) {
      int c = t + q*512;
      int j = c >> 4, dd0 = (c & 15) * 8;
      *(bf16x8*)((char*)Kl + ((j*256 + dd0*2) ^ ((j & 7) << 4))) = kr[q];
      int ks = j >> 5, jq = j & 31;
      int cc = dd0 >> 4;
      int wb = ks*8192 + cc*1024 + (((dd0 & 15) + 16*((jq >> 3) & 3)) & ~7)*16 + (jq & 7)*2;
      #pragma unroll
      for (int e = 0; e < 8; ++e)
        *(unsigned short*)((char*)Vf + wb + ((e ^ cc) * 16)) = (unsigned short)vr[q][e];
    }
    __syncthreads();
    if (kt + 1 < nkt) loadKV(kt + 1);    // prefetch during compute

    if (kt <= dt) {
      // ---- QK^T: scores [16 rows][64 cols] per wave ----
      f32x4 sc[4] = {};
      #pragma unroll
      for (int jt = 0; jt < 4; ++jt) {
        int row = jt*16 + l15;
        const char* kb = (const char*)Kl + row*256;
        const int sw = (row & 7) << 4;
        #pragma unroll
        for (int c = 0; c < 4; ++c) {
          bf16x8 kf = *(const bf16x8*)(kb + ((c*64 + lh*16) ^ sw));
          sc[jt] = __builtin_amdgcn_mfma_f32_16x16x32_bf16(qf[c], kf, sc[jt], 0, 0, 0);
        }
      }

      // ---- online softmax ----
      float fac[4];
      char* pw = (char*)Pl + wave*2048;
      #pragma unroll
      for (int r = 0; r < 4; ++r) {
        float s0 = sc[0][r]*SCALE, s1 = sc[1][r]*SCALE, s2 = sc[2][r]*SCALE, s3 = sc[3][r]*SCALE;
        if (kt == dt) {
          const int i = i0 + lh*4 + r;
          const int j = kt*64 + l15;
          s0 = (j      > i) ? -INFINITY : s0;
          s1 = (j + 16 > i) ? -INFINITY : s1;
          s2 = (j + 32 > i) ? -INFINITY : s2;
          s3 = (j + 48 > i) ? -INFINITY : s3;
        }
        float mx = fmaxf(fmaxf(s0, s1), fmaxf(s2, s3));
        #pragma unroll
        for (int mk = 1; mk < 16; mk <<= 1) mx = fmaxf(mx, __shfl_xor(mx, mk));
        const float mnew = fmaxf(mrun[r], mx);
        float p0 = __expf(s0 - mnew), p1 = __expf(s1 - mnew);
        float p2 = __expf(s2 - mnew), p3 = __expf(s3 - mnew);
        float psum = (p0 + p1) + (p2 + p3);
        #pragma unroll
        for (int mk = 1; mk < 16; mk <<= 1) psum += __shfl_xor(psum, mk);
        fac[r]  = __expf(mrun[r] - mnew);
        lrun[r] = lrun[r]*fac[r] + psum;
        mrun[r] = mnew;
        const int io = lh*4 + r;
        const int swp = (io & 7) << 4;
        char* pr = pw + io*128;
        *(unsigned short*)(pr + ((     l15*2) ^ swp)) = f2bf(p0);
        *(unsigned short*)(pr + ((32 + l15*2) ^ swp)) = f2bf(p1);
        *(unsigned short*)(pr + ((64 + l15*2) ^ swp)) = f2bf(p2);
        *(unsigned short*)(pr + ((96 + l15*2) ^ swp)) = f2bf(p3);
      }
      #pragma unroll
      for (int c = 0; c < 8; ++c)
        #pragma unroll
        for (int r = 0; r < 4; ++r)
          of[c][r] *= fac[r];

      // ---- P fragments (per-wave LDS transpose, row-XOR) ----
      const char* prd = pw + l15*128;
      const int psw = (l15 & 7) << 4;
      bf16x8 pa0 = *(const bf16x8*)(prd + ((     lh*16) ^ psw));
      bf16x8 pa1 = *(const bf16x8*)(prd + ((64 + lh*16) ^ psw));

      // ---- PV: o[16][128] += P[16][64] @ V[64][128] ----
      #pragma unroll
      for (int c = 0; c < 8; ++c) {
        const char* vb = (const char*)Vf + c*1024 + ((lane ^ c) * 16);
        bf16x8 v0 = *(const bf16x8*)(vb);
        bf16x8 v1 = *(const bf16x8*)(vb + 8192);
        of[c] = __builtin_amdgcn_mfma_f32_16x16x32_bf16(pa0, v0, of[c], 0, 0, 0);
        of[c] = __builtin_amdgcn_mfma_f32_16x16x32_bf16(pa1, v1, of[c], 0, 0, 0);
      }
    }
  }

  // ---- normalize + store ----
  unsigned short* orow = O + ((size_t)(b*2048 + i0))*2048 + nh*128;
  #pragma unroll
  for (int r = 0; r < 4; ++r) {
    const float inv = 1.f / lrun[r];
    #pragma unroll
    for (int c = 0; c < 8; ++c)
      orow[(size_t)(lh*4 + r)*2048 + c*16 + l15] = f2bf(of[c][r]*inv);
  }
}

// ---------------- launcher ----------------
extern "C" void kernel_launch(void* const* d_in, const int* in_sizes, int n_in,
                              void* d_out, int out_size, void* d_ws, size_t ws_size,
                              hipStream_t stream)
{
  const float* x    = (const float*)d_in[0];
  const float* Wq   = (const float*)d_in[2];
  const float* Wk   = (const float*)d_in[3];
  const float* Wv   = (const float*)d_in[4];
  const float* Wo   = (const float*)d_in[5];
  const float* ln1g = (const float*)d_in[6];
  const float* ln1b = (const float*)d_in[7];
  const float* W1   = (const float*)d_in[8];
  const float* b1   = (const float*)d_in[9];
  const float* W2   = (const float*)d_in[10];
  const float* b2   = (const float*)d_in[11];
  const float* ln2g = (const float*)d_in[12];
  const float* ln2b = (const float*)d_in[13];
  float* out = (float*)d_out;

  char* ws = (char*)d_ws;
  unsigned short* WqkvT  = (unsigned short*)(ws);                  // [6144][2048] bf16
  unsigned short* WoT    = (unsigned short*)(ws + 25165824);       // [2048][2048]
  unsigned short* W1T    = (unsigned short*)(ws + 33554432);       // [8192][2048]
  unsigned short* W2T    = (unsigned short*)(ws + 67108864);       // [2048][8192]
  unsigned short* h      = (unsigned short*)(ws + 100663296);      // [4096][2048]
  float*          x2     = (float*)(ws + 117440512);               // [4096][2048] f32
  unsigned short* QKV    = (unsigned short*)(ws + 150994944);      // [4096][6144]
  unsigned short* attn_o = (unsigned short*)(ws + 201326592);      // [4096][2048]
  unsigned short* ff1    = (unsigned short*)(ws + 150994944);      // [4096][8192]
  float*          Pws    = (float*)(ws);                           // [2][4096][2048] f32
  // Pws overlays WqkvT/WoT/W1T (0..64MB) — all dead by the time W2 runs;
  // rebuilt at the start of every kernel_launch call (graph-replay safe).

  dim3 tb(32, 8);
  TPArgs tp;
  tp.src[0] = Wq; tp.dst[0] = WqkvT;
  tp.src[1] = Wk; tp.dst[1] = WqkvT + 2048*2048;
  tp.src[2] = Wv; tp.dst[2] = WqkvT + 2*2048*2048;
  tp.src[3] = Wo; tp.dst[3] = WoT;
  transpose_cast4<<<dim3(64, 64, 4), tb, 0, stream>>>(tp);
  transpose_cast<<<dim3(256, 64), tb, 0, stream>>>(W1, W1T, 2048, 8192);
  transpose_cast<<<dim3(64, 256), tb, 0, stream>>>(W2, W2T, 8192, 2048);

  ln_kernel<<<4096, 256, 0, stream>>>(x, ln1g, ln1b, h);
  // QKV = h @ [Wq|Wk|Wv]   (M=4096, N=6144, K=2048): 16x24 = 384 blocks
  gemm8<256,false,false,false,true><<<384, 512, 0, stream>>>(
      h, WqkvT, nullptr, nullptr, QKV, 4096, 6144, 2048, 2048, 24, 384);
  attn_kernel<<<512, 512, 0, stream>>>(QKV, attn_o);
  // x2 = x + attn_o @ Wo   (N=2048): BM=128 -> 32x8 = 256 blocks
  gemm8<128,false,false,true,false><<<256, 512, 0, stream>>>(
      attn_o, WoT, nullptr, x, x2, 4096, 2048, 2048, 2048, 8, 256);
  ln_kernel<<<4096, 256, 0, stream>>>(x2, ln2g, ln2b, h);
  // ff1 = relu(h2 @ W1 + b1)  (N=8192): 16x32 = 512 blocks
  gemm8<256,true,true,false,true><<<512, 512, 0, stream>>>(
      h, W1T, b1, nullptr, ff1, 4096, 8192, 2048, 2048, 32, 512);
  // W2 split-K=2: partials P[s] = ff1[:, s*4096:(s+1)*4096] @ W2T-half
  gemm8<256,false,false,false,false><<<256, 512, 0, stream>>>(
      ff1, W2T, nullptr, nullptr, Pws, 4096, 2048, 8192, 4096, 8, 128);
  // out = x2 + P0 + P1 + b2
  reduce_splitk<<<2048, 256, 0, stream>>>(Pws, x2, b2, out);
}